// Round 9
// baseline (485.126 us; speedup 1.0000x reference)
//
#include <hip/hip_runtime.h>

// ============================================================================
// LeViT attention, MI355X. I/O tensors are FLOAT32 (per reference).
// b=2, C=256, H=W=56, n=3136, heads=8, kd=16, dh=64.
// Pipeline: xtw (x->x_t bf16 + W'=s*W bf16, one launch) -> qkv (MFMA, no LDS,
// q pre-scaled by log2e) -> attn (flash, all-mfma32, key-interleaved padded
// LDS, VGPR-staged double buffer, raw s_barrier w/o vmcnt drain, rsum via
// ones-MFMA) -> proj (MFMA, no LDS, fp32 out).
// ws (u16 elems): qws 802816 | kws 802816 | vws 3211264 | R 3211264
//   (R = x_t during xtw/qkv, o_t from attn on) | wqb 32768 | wkb 32768 |
//   wvb 131072 | wpb 131072   => 16,711,680 B
// MFMA 16x16x32_bf16: A[m=l15][k=quad*8+j]; B[k=quad*8+j][n=l15];
// C/D: col=l15, row=quad*4+reg.
// attn key relabeling (softmax is key-permutation invariant; no running max):
//   B k-slot (quad*8 + t*4 + r) <- actual key (c32*32 + t*16 + quad*4 + r),
//   so P = concat of two S^T C-tiles with ZERO data movement, and V sits in
//   LDS at pos = c32*32 + q4*8 + t*4 + r (one b128 per PV A-frag).
// ============================================================================

typedef short  s16x8 __attribute__((ext_vector_type(8)));
typedef short  s16x4 __attribute__((ext_vector_type(4)));
typedef float  f32x4 __attribute__((ext_vector_type(4)));
typedef unsigned short u16;
typedef unsigned short u16x4 __attribute__((ext_vector_type(4)));

__device__ __forceinline__ u16 f2bf(float f) {   // RNE
    unsigned u = __builtin_bit_cast(unsigned, f);
    u += 0x7FFF + ((u >> 16) & 1);
    return (u16)(u >> 16);
}
__device__ __forceinline__ u16 f2bf_h(float f) { // round-half-up (cheap)
    unsigned u = __builtin_bit_cast(unsigned, f);
    return (u16)((u + 0x8000) >> 16);
}
__device__ __forceinline__ f32x4 mfma32(s16x8 a, s16x8 b, f32x4 c) {
    return __builtin_amdgcn_mfma_f32_16x16x32_bf16(a, b, c, 0, 0, 0);
}

// ---------------------------------------------------------------------------
// Fused: z<2 -> x[b][256][3136] fp32 -> x_t[b][3136][256] bf16 transpose;
//        z==2 -> W' = s*W bf16 fold. grid (49,4,3), 256 thr.
// ---------------------------------------------------------------------------
__global__ __launch_bounds__(256) void xtw_kernel(
    const float* __restrict__ x, u16* __restrict__ xt,
    const float* __restrict__ wq, const float* __restrict__ sq,
    const float* __restrict__ wk, const float* __restrict__ sk,
    const float* __restrict__ wv, const float* __restrict__ sv,
    const float* __restrict__ wp, const float* __restrict__ sp,
    u16* __restrict__ wqb, u16* __restrict__ wkb,
    u16* __restrict__ wvb, u16* __restrict__ wpb)
{
    const int t = threadIdx.x;
    if (blockIdx.z == 2) {
        const int base = (blockIdx.y * 49 + blockIdx.x) * 256 + t;
        for (int idx = base; idx < 327680; idx += 50176) {
            if (idx < 32768)        wqb[idx] = f2bf(wq[idx] * sq[idx >> 8]);
            else if (idx < 65536)  { int j = idx - 32768;  wkb[j] = f2bf(wk[j] * sk[j >> 8]); }
            else if (idx < 196608) { int j = idx - 65536;  wvb[j] = f2bf(wv[j] * sv[j >> 8]); }
            else                   { int j = idx - 196608; wpb[j] = f2bf(wp[j] * sp[j >> 9]); }
        }
        return;
    }
    const int b = blockIdx.z, c0 = blockIdx.y * 64, n0 = blockIdx.x * 64;
    __shared__ float lds[64][65];
    const int nl = t & 63, cl = t >> 6;
    #pragma unroll
    for (int i = 0; i < 16; i++) {
        const int c = cl + i * 4;
        lds[c][nl] = x[(b * 256 + c0 + c) * 3136 + n0 + nl];
    }
    __syncthreads();
    #pragma unroll
    for (int i = 0; i < 16; i++) {
        const int n = cl + i * 4;
        xt[(b * 3136 + n0 + n) * 256 + c0 + nl] = f2bf(lds[nl][n]);
    }
}

// ---------------------------------------------------------------------------
// QKV MFMA GEMM, no LDS. grid (49 n-tiles, 12 rt, 2 b), 256 thr.
// rt 0..3: q/k (token-major store; q pre-scaled by log2e); rt 4..11: v.
// ---------------------------------------------------------------------------
__global__ __launch_bounds__(256, 4) void qkv_kernel(
    const u16* __restrict__ xt,
    const u16* __restrict__ wqb, const u16* __restrict__ wkb, const u16* __restrict__ wvb,
    const float* __restrict__ bq, const float* __restrict__ bk, const float* __restrict__ bv,
    u16* __restrict__ qws, u16* __restrict__ kws, u16* __restrict__ vws)
{
    const int b = blockIdx.z, rt = blockIdx.y, n0 = blockIdx.x * 64;
    const int t = threadIdx.x, wave = t >> 6, lane = t & 63;
    const int l15 = lane & 15, quad = lane >> 4;
    const f32x4 z = {0.f, 0.f, 0.f, 0.f};

    if (rt < 4) {
        const u16* wb      = (rt < 2) ? wqb : wkb;
        const float* bias  = (rt < 2) ? bq : bk;
        u16* dst           = (rt < 2) ? qws : kws;
        const float qs     = (rt < 2) ? 1.44269504088896f : 1.0f;  // fold log2e
        const int och0 = (rt & 1) * 64;
        const int m0   = n0 + wave * 16;
        const u16* xrow = &xt[(b * 3136 + m0 + l15) * 256 + quad * 8];
        f32x4 acc[4] = {z, z, z, z};
        #pragma unroll
        for (int kc = 0; kc < 256; kc += 32) {
            s16x8 a = *(const s16x8*)&xrow[kc];
            #pragma unroll
            for (int f = 0; f < 4; f++) {
                s16x8 bf = *(const s16x8*)&wb[(och0 + f * 16 + l15) * 256 + kc + quad * 8];
                acc[f] = mfma32(a, bf, acc[f]);
            }
        }
        #pragma unroll
        for (int f = 0; f < 4; f++) {
            const int och = och0 + f * 16 + l15;
            const float bi = bias[och];
            const int h = och >> 4;
            #pragma unroll
            for (int r = 0; r < 4; r++) {
                const int tok = m0 + quad * 4 + r;
                dst[((b * 8 + h) * 3136 + tok) * 16 + l15] = f2bf((acc[f][r] + bi) * qs);
            }
        }
    } else {
        const int och0 = (rt - 4) * 64 + wave * 16;
        const u16* arow = &wvb[(och0 + l15) * 256 + quad * 8];
        f32x4 acc[4] = {z, z, z, z};
        #pragma unroll
        for (int kc = 0; kc < 256; kc += 32) {
            s16x8 a = *(const s16x8*)&arow[kc];
            #pragma unroll
            for (int f = 0; f < 4; f++) {
                s16x8 bf = *(const s16x8*)&xt[(b * 3136 + n0 + f * 16 + l15) * 256 + kc + quad * 8];
                acc[f] = mfma32(a, bf, acc[f]);
            }
        }
        #pragma unroll
        for (int r = 0; r < 4; r++) {
            const int och = och0 + quad * 4 + r;
            const float bi = bv[och];
            #pragma unroll
            for (int f = 0; f < 4; f++) {
                const int tok = n0 + f * 16 + l15;
                vws[(b * 512 + och) * 3136 + tok] = f2bf(acc[f][r] + bi);
            }
        }
    }
}

// ---------------------------------------------------------------------------
// Flash attention v8. grid (16 bh, 49 q-tiles of 64); 4 waves; 49 key-chunks
// of 64. Double-buffered padded LDS (K stride 18, V stride 70, interleaved),
// VGPR staging 2 chunks ahead; raw s_barrier + lgkmcnt(0) only (global loads
// stay in flight across the barrier — they land in private VGPRs).
// ---------------------------------------------------------------------------
__global__ __launch_bounds__(256, 4) void attn_kernel(
    const u16* __restrict__ qws, const u16* __restrict__ kws,
    const u16* __restrict__ vws, u16* __restrict__ o_t)
{
    const int bh   = blockIdx.x;                 // x fastest -> XCD = bh%8
    const int tile = blockIdx.y;
    const int t    = threadIdx.x;
    const int wave = t >> 6, lane = t & 63;
    const int l15  = lane & 15, quad = lane >> 4;
    const int nb   = tile * 64 + wave * 16;      // this wave's query base

    __shared__ __align__(16) u16 kbuf[2][64 * 18];   // [key][d half] pad 18
    __shared__ __align__(16) u16 vbuf[2][64 * 70];   // [d][interleaved key] pad 70

    const u16* kb = &kws[bh * 3136 * 16];
    const u16* vb = &vws[bh * 64 * 3136];

    // staging geometry (per lane, chunk-invariant)
    const int vd   = lane >> 3;                  // d within 8-row segment
    const int voct = lane & 7;                   // source key-octet
    const int weff = wave & 1;                   // wave pairs duplicate K halves
    const int kkey = lane >> 1, khalf = lane & 1;
    // V dest interleave: pos = c32*32 + h*16 + (s>>2)*8 + t*4 + (s&3)
    const int vdst = (voct >> 2) * 32 + (voct & 1) * 16 + ((voct >> 1) & 1) * 4;
    const int kdst = (weff * 32 + kkey) * 18 + khalf * 8;

    // Q fragment (B-op): B[k=d=quad*8+j][n=query=l15]; zero for d>=16
    s16x8 aq = {0, 0, 0, 0, 0, 0, 0, 0};
    if (quad < 2)
        aq = *(const s16x8*)&qws[(bh * 3136 + nb + l15) * 16 + quad * 8];
    s16x8 ones;
    #pragma unroll
    for (int i = 0; i < 8; i++) ones[i] = (short)0x3F80;   // bf16 1.0

    f32x4 acc[4], acc5;                          // O^T tiles + rowsum tile
    #pragma unroll
    for (int dt = 0; dt < 4; dt++) acc[dt] = (f32x4){0.f, 0.f, 0.f, 0.f};
    acc5 = (f32x4){0.f, 0.f, 0.f, 0.f};

    // ---- preamble: load+write chunk0, load chunk1
    s16x8 vr0 = *(const s16x8*)&vb[(wave * 8 + vd) * 3136 + voct * 8];
    s16x8 vr1 = *(const s16x8*)&vb[((wave + 4) * 8 + vd) * 3136 + voct * 8];
    s16x8 kr  = *(const s16x8*)&kb[(weff * 32 + kkey) * 16 + khalf * 8];
    {
        u16* d0 = &vbuf[0][(wave * 8 + vd) * 70 + vdst];
        u16* d1 = &vbuf[0][((wave + 4) * 8 + vd) * 70 + vdst];
        *(s16x4*)d0 = (s16x4){vr0[0], vr0[1], vr0[2], vr0[3]};
        *(s16x4*)(d0 + 8) = (s16x4){vr0[4], vr0[5], vr0[6], vr0[7]};
        *(s16x4*)d1 = (s16x4){vr1[0], vr1[1], vr1[2], vr1[3]};
        *(s16x4*)(d1 + 8) = (s16x4){vr1[4], vr1[5], vr1[6], vr1[7]};
        *(s16x8*)&kbuf[0][kdst] = kr;
    }
    vr0 = *(const s16x8*)&vb[(wave * 8 + vd) * 3136 + 64 + voct * 8];
    vr1 = *(const s16x8*)&vb[((wave + 4) * 8 + vd) * 3136 + 64 + voct * 8];
    kr  = *(const s16x8*)&kb[(64 + weff * 32 + kkey) * 16 + khalf * 8];
    __builtin_amdgcn_s_waitcnt(0xC07F);          // lgkmcnt(0) only
    __builtin_amdgcn_s_barrier();

    for (int c = 0; c < 49; c++) {
        const int cur = c & 1, nxt = cur ^ 1;

        // ---- (A) LDS-write chunk c+1 from staged VGPRs (compiler vm-waits)
        {
            u16* d0 = &vbuf[nxt][(wave * 8 + vd) * 70 + vdst];
            u16* d1 = &vbuf[nxt][((wave + 4) * 8 + vd) * 70 + vdst];
            *(s16x4*)d0 = (s16x4){vr0[0], vr0[1], vr0[2], vr0[3]};
            *(s16x4*)(d0 + 8) = (s16x4){vr0[4], vr0[5], vr0[6], vr0[7]};
            *(s16x4*)d1 = (s16x4){vr1[0], vr1[1], vr1[2], vr1[3]};
            *(s16x4*)(d1 + 8) = (s16x4){vr1[4], vr1[5], vr1[6], vr1[7]};
            *(s16x8*)&kbuf[nxt][kdst] = kr;
        }
        // ---- (B) issue global loads for chunk c+2 (in flight across barrier)
        const int k2 = (c + 2 < 49) ? (c + 2) * 64 : 48 * 64;
        vr0 = *(const s16x8*)&vb[(wave * 8 + vd) * 3136 + k2 + voct * 8];
        vr1 = *(const s16x8*)&vb[((wave + 4) * 8 + vd) * 3136 + k2 + voct * 8];
        kr  = *(const s16x8*)&kb[(k2 + weff * 32 + kkey) * 16 + khalf * 8];

        // ---- (C) compute chunk c
        const u16* kc_ = kbuf[cur];
        const u16* vc_ = vbuf[cur];
        const f32x4 z = {0.f, 0.f, 0.f, 0.f};
        f32x4 s[4];
        #pragma unroll
        for (int i = 0; i < 4; i++) {
            s16x8 kf = *(const s16x8*)&kc_[(i * 16 + l15) * 18 + (quad & 1) * 8];
            s[i] = mfma32(kf, aq, z);            // S^T tile: rows=key, cols=query
        }
        // P pack: pf[c32] = {exp2 s[2c32] , exp2 s[2c32+1]} (q pre-scaled log2e)
        s16x8 pf[2];
        #pragma unroll
        for (int c32 = 0; c32 < 2; c32++) {
            #pragma unroll
            for (int r = 0; r < 4; r++) {
                pf[c32][r]     = (short)f2bf_h(__builtin_amdgcn_exp2f(s[2 * c32][r]));
                pf[c32][4 + r] = (short)f2bf_h(__builtin_amdgcn_exp2f(s[2 * c32 + 1][r]));
            }
        }
        // O^T += V^T·P (interleaved keys -> one b128 per A-frag); rowsum MFMA
        #pragma unroll
        for (int c32 = 0; c32 < 2; c32++) {
            #pragma unroll
            for (int dt = 0; dt < 4; dt++) {
                s16x8 vf = *(const s16x8*)&vc_[(dt * 16 + l15) * 70 + c32 * 32 + quad * 8];
                acc[dt] = mfma32(vf, pf[c32], acc[dt]);
            }
            acc5 = mfma32(ones, pf[c32], acc5);
        }

        // ---- (D) fence LDS, barrier WITHOUT vmcnt drain
        __builtin_amdgcn_s_waitcnt(0xC07F);      // lgkmcnt(0)
        __builtin_amdgcn_s_barrier();
    }

    const float inv = 1.0f / acc5[0];            // rowsum for query l15 (all regs equal)

    // ---- epilogue: O^T rows d = dt*16+quad*4+r, col query l15 -> o_t[n][512]
    u16* dst = &o_t[(((bh >> 3) * 3136) + nb + l15) * 512 + (bh & 7) * 64];
    #pragma unroll
    for (int dt = 0; dt < 4; dt++) {
        u16x4 o4;
        #pragma unroll
        for (int r = 0; r < 4; r++) o4[r] = f2bf(acc[dt][r] * inv);
        *(u16x4*)&dst[dt * 16 + quad * 4] = o4;
    }
}

// ---------------------------------------------------------------------------
// Output projection MFMA GEMM, no LDS. grid (98 n-tiles of 32, 4 och, 2 b).
// ---------------------------------------------------------------------------
__global__ __launch_bounds__(256, 4) void proj_kernel(
    const u16* __restrict__ o_t, const u16* __restrict__ wpb,
    const float* __restrict__ bp, float* __restrict__ out)
{
    const int b = blockIdx.z, n0 = blockIdx.x * 32;
    const int och0 = blockIdx.y * 64 + (threadIdx.x >> 6) * 16;
    const int lane = threadIdx.x & 63;
    const int l15 = lane & 15, quad = lane >> 4;
    const f32x4 z = {0.f, 0.f, 0.f, 0.f};

    const u16* arow = &wpb[(och0 + l15) * 512 + quad * 8];
    f32x4 acc[2] = {z, z};
    #pragma unroll 4
    for (int kc = 0; kc < 512; kc += 32) {
        s16x8 a = *(const s16x8*)&arow[kc];
        #pragma unroll
        for (int f = 0; f < 2; f++) {
            s16x8 bf = *(const s16x8*)&o_t[(b * 3136 + n0 + f * 16 + l15) * 512 + kc + quad * 8];
            acc[f] = mfma32(a, bf, acc[f]);
        }
    }
    #pragma unroll
    for (int r = 0; r < 4; r++) {
        const int och = och0 + quad * 4 + r;
        const float bi = bp[och];
        #pragma unroll
        for (int f = 0; f < 2; f++)
            out[(b * 256 + och) * 3136 + n0 + f * 16 + l15] = acc[f][r] + bi;
    }
}

// ---------------------------------------------------------------------------
extern "C" void kernel_launch(void* const* d_in, const int* in_sizes, int n_in,
                              void* d_out, int out_size, void* d_ws, size_t ws_size,
                              hipStream_t stream) {
    const float* x  = (const float*)d_in[0];
    const float* wq = (const float*)d_in[1];
    const float* sq = (const float*)d_in[2];
    const float* bq = (const float*)d_in[3];
    const float* wk = (const float*)d_in[4];
    const float* sk = (const float*)d_in[5];
    const float* bk = (const float*)d_in[6];
    const float* wv = (const float*)d_in[7];
    const float* sv = (const float*)d_in[8];
    const float* bv = (const float*)d_in[9];
    const float* wp = (const float*)d_in[10];
    const float* sp = (const float*)d_in[11];
    const float* bp = (const float*)d_in[12];
    float* out = (float*)d_out;

    u16* qws = (u16*)d_ws;                 // 802816
    u16* kws = qws + 802816;               // 802816
    u16* vws = kws + 802816;               // 3211264
    u16* R   = vws + 3211264;              // 3211264 (x_t then o_t, overlaid)
    u16* xt  = R;
    u16* ot  = R;
    u16* wqb = R + 3211264;                // 32768
    u16* wkb = wqb + 32768;                // 32768
    u16* wvb = wkb + 32768;                // 131072
    u16* wpb = wvb + 131072;               // 131072  (total 16,711,680 B)

    xtw_kernel<<<dim3(49, 4, 3), 256, 0, stream>>>(x, xt, wq, sq, wk, sk,
                                                   wv, sv, wp, sp,
                                                   wqb, wkb, wvb, wpb);
    qkv_kernel<<<dim3(49, 12, 2), 256, 0, stream>>>(xt, wqb, wkb, wvb,
                                                    bq, bk, bv, qws, kws, vws);
    attn_kernel<<<dim3(16, 49), 256, 0, stream>>>(qws, kws, vws, ot);
    proj_kernel<<<dim3(98, 4, 2), 256, 0, stream>>>(ot, wpb, bp, out);
}

// Round 10
// 202.301 us; speedup vs baseline: 2.3980x; 2.3980x over previous
//
#include <hip/hip_runtime.h>

// ============================================================================
// LeViT attention, MI355X. I/O tensors are FLOAT32 (per reference).
// b=2, C=256, H=W=56, n=3136, heads=8, kd=16, dh=64.
// Pipeline: xtw (x->x_t bf16 + W'=s*W bf16) -> qkv (MFMA, no LDS, q scaled by
// log2e) -> attn (flash; r8's proven global_load_lds triple-buffer/vmcnt/
// s_barrier structure + r9's proven key-relabeled interleave so PV runs on
// mfma32 with conflict-free b128 reads) -> proj (MFMA, no LDS, fp32 out).
// ws (u16 elems): qws 802816 | kws 802816 | vws 3211264 | R 3211264
//   (R = x_t during xtw/qkv, o_t from attn on) | wqb 32768 | wkb 32768 |
//   wvb 131072 | wpb 131072   => 16,711,680 B
// MFMA 16x16x32_bf16: A[m=l15][k=quad*8+j]; B[k=quad*8+j][n=l15];
// C/D: col=l15, row=quad*4+reg.
// attn key relabeling (softmax key-permutation invariant; no running max):
//   slot pos = c32*32 + quad*8 + t*4 + r  <-  actual key c32*32 + t*16 + quad*4 + r
//   => P = concat of two S^T C-tiles (zero movement); V stored interleaved in
//   LDS, octet o_rel=c32*4+quad of row d at position o_rel^(d&7) (bank-free).
// ============================================================================

typedef short  s16x8 __attribute__((ext_vector_type(8)));
typedef float  f32x4 __attribute__((ext_vector_type(4)));
typedef unsigned short u16;
typedef unsigned short u16x4 __attribute__((ext_vector_type(4)));

__device__ __forceinline__ u16 f2bf(float f) {   // RNE
    unsigned u = __builtin_bit_cast(unsigned, f);
    u += 0x7FFF + ((u >> 16) & 1);
    return (u16)(u >> 16);
}
__device__ __forceinline__ u16 f2bf_h(float f) { // round-half-up (cheap, p>0)
    unsigned u = __builtin_bit_cast(unsigned, f);
    return (u16)((u + 0x8000) >> 16);
}
__device__ __forceinline__ f32x4 mfma32(s16x8 a, s16x8 b, f32x4 c) {
    return __builtin_amdgcn_mfma_f32_16x16x32_bf16(a, b, c, 0, 0, 0);
}
__device__ __forceinline__ void stage16(const u16* g, u16* l) {
    __builtin_amdgcn_global_load_lds(
        (const __attribute__((address_space(1))) unsigned int*)g,
        (__attribute__((address_space(3))) unsigned int*)l, 16, 0, 0);
}
__device__ __forceinline__ void stage4(const u16* g, u16* l) {
    __builtin_amdgcn_global_load_lds(
        (const __attribute__((address_space(1))) unsigned int*)g,
        (__attribute__((address_space(3))) unsigned int*)l, 4, 0, 0);
}

// ---------------------------------------------------------------------------
// Fused: z<2 -> x fp32 -> x_t[b][3136][256] bf16 transpose; z==2 -> W'=s*W.
// grid (49,4,3), 256 thr.
// ---------------------------------------------------------------------------
__global__ __launch_bounds__(256) void xtw_kernel(
    const float* __restrict__ x, u16* __restrict__ xt,
    const float* __restrict__ wq, const float* __restrict__ sq,
    const float* __restrict__ wk, const float* __restrict__ sk,
    const float* __restrict__ wv, const float* __restrict__ sv,
    const float* __restrict__ wp, const float* __restrict__ sp,
    u16* __restrict__ wqb, u16* __restrict__ wkb,
    u16* __restrict__ wvb, u16* __restrict__ wpb)
{
    const int t = threadIdx.x;
    if (blockIdx.z == 2) {
        const int base = (blockIdx.y * 49 + blockIdx.x) * 256 + t;
        for (int idx = base; idx < 327680; idx += 50176) {
            if (idx < 32768)        wqb[idx] = f2bf(wq[idx] * sq[idx >> 8]);
            else if (idx < 65536)  { int j = idx - 32768;  wkb[j] = f2bf(wk[j] * sk[j >> 8]); }
            else if (idx < 196608) { int j = idx - 65536;  wvb[j] = f2bf(wv[j] * sv[j >> 8]); }
            else                   { int j = idx - 196608; wpb[j] = f2bf(wp[j] * sp[j >> 9]); }
        }
        return;
    }
    const int b = blockIdx.z, c0 = blockIdx.y * 64, n0 = blockIdx.x * 64;
    __shared__ float lds[64][65];
    const int nl = t & 63, cl = t >> 6;
    #pragma unroll
    for (int i = 0; i < 16; i++) {
        const int c = cl + i * 4;
        lds[c][nl] = x[(b * 256 + c0 + c) * 3136 + n0 + nl];
    }
    __syncthreads();
    #pragma unroll
    for (int i = 0; i < 16; i++) {
        const int n = cl + i * 4;
        xt[(b * 3136 + n0 + n) * 256 + c0 + nl] = f2bf(lds[nl][n]);
    }
}

// ---------------------------------------------------------------------------
// QKV MFMA GEMM, no LDS. grid (49 n-tiles, 12 rt, 2 b), 256 thr.
// rt 0..3: q/k (token-major store; q pre-scaled by log2e); rt 4..11: v.
// ---------------------------------------------------------------------------
__global__ __launch_bounds__(256, 4) void qkv_kernel(
    const u16* __restrict__ xt,
    const u16* __restrict__ wqb, const u16* __restrict__ wkb, const u16* __restrict__ wvb,
    const float* __restrict__ bq, const float* __restrict__ bk, const float* __restrict__ bv,
    u16* __restrict__ qws, u16* __restrict__ kws, u16* __restrict__ vws)
{
    const int b = blockIdx.z, rt = blockIdx.y, n0 = blockIdx.x * 64;
    const int t = threadIdx.x, wave = t >> 6, lane = t & 63;
    const int l15 = lane & 15, quad = lane >> 4;
    const f32x4 z = {0.f, 0.f, 0.f, 0.f};

    if (rt < 4) {
        const u16* wb      = (rt < 2) ? wqb : wkb;
        const float* bias  = (rt < 2) ? bq : bk;
        u16* dst           = (rt < 2) ? qws : kws;
        const float qs     = (rt < 2) ? 1.44269504088896f : 1.0f;  // fold log2e
        const int och0 = (rt & 1) * 64;
        const int m0   = n0 + wave * 16;
        const u16* xrow = &xt[(b * 3136 + m0 + l15) * 256 + quad * 8];
        f32x4 acc[4] = {z, z, z, z};
        #pragma unroll
        for (int kc = 0; kc < 256; kc += 32) {
            s16x8 a = *(const s16x8*)&xrow[kc];
            #pragma unroll
            for (int f = 0; f < 4; f++) {
                s16x8 bf = *(const s16x8*)&wb[(och0 + f * 16 + l15) * 256 + kc + quad * 8];
                acc[f] = mfma32(a, bf, acc[f]);
            }
        }
        #pragma unroll
        for (int f = 0; f < 4; f++) {
            const int och = och0 + f * 16 + l15;
            const float bi = bias[och];
            const int h = och >> 4;
            #pragma unroll
            for (int r = 0; r < 4; r++) {
                const int tok = m0 + quad * 4 + r;
                dst[((b * 8 + h) * 3136 + tok) * 16 + l15] = f2bf((acc[f][r] + bi) * qs);
            }
        }
    } else {
        const int och0 = (rt - 4) * 64 + wave * 16;
        const u16* arow = &wvb[(och0 + l15) * 256 + quad * 8];
        f32x4 acc[4] = {z, z, z, z};
        #pragma unroll
        for (int kc = 0; kc < 256; kc += 32) {
            s16x8 a = *(const s16x8*)&arow[kc];
            #pragma unroll
            for (int f = 0; f < 4; f++) {
                s16x8 bf = *(const s16x8*)&xt[(b * 3136 + n0 + f * 16 + l15) * 256 + kc + quad * 8];
                acc[f] = mfma32(a, bf, acc[f]);
            }
        }
        #pragma unroll
        for (int r = 0; r < 4; r++) {
            const int och = och0 + quad * 4 + r;
            const float bi = bv[och];
            #pragma unroll
            for (int f = 0; f < 4; f++) {
                const int tok = n0 + f * 16 + l15;
                vws[(b * 512 + och) * 3136 + tok] = f2bf(acc[f][r] + bi);
            }
        }
    }
}

// ---------------------------------------------------------------------------
// Flash attention v9 = r8 structure + relabeled-interleave mfma32 PV.
// grid (16 bh, 49 q-tiles of 64); 4 waves; 49 key-chunks of 64, triple-
// buffered LDS via global_load_lds (V: 8 dword-DMA/wave w/ interleave+row-xor;
// K: 1 dwordx4-DMA/wave). One raw s_barrier + vmcnt(9) per chunk.
// ---------------------------------------------------------------------------
__global__ __launch_bounds__(256, 4) void attn_kernel(
    const u16* __restrict__ qws, const u16* __restrict__ kws,
    const u16* __restrict__ vws, u16* __restrict__ o_t)
{
    const int bh   = blockIdx.x;                 // x fastest -> XCD = bh%8
    const int tile = blockIdx.y;
    const int t    = threadIdx.x;
    const int wave = t >> 6, lane = t & 63;
    const int l15  = lane & 15, quad = lane >> 4;
    const int nb   = tile * 64 + wave * 16;      // this wave's query base

    // per buffer: K 1024 u16 (64 keys x 16 d) | V 4096 u16 (64 d x 64 slots)
    __shared__ __align__(16) u16 stg[3][5120];

    const u16* kb = &kws[bh * 3136 * 16];
    const u16* vb = &vws[bh * 64 * 3136];

    // ---- K staging geometry (r8, proven): 1 x 16B DMA per wave
    const int weff  = wave & 1;                  // wave pairs duplicate K halves
    const int kkey  = lane >> 1;
    const int khalf = (lane & 1) ^ ((lane >> 3) & 1);   // half swizzle
    const int kdst  = weff * 512;                // dest base elems (uniform)
    const int ksrc_row = weff * 32 + kkey;       // + khalf*8 within row

    // ---- V staging geometry: 8 x 4B DMA per wave, 2 rows (256B) each.
    // dest = stg[buf][1024 + m*128elems] + lane*2 elems; m = wave + s*4.
    // lane -> d = 2m + (lane>>5), dwpos = lane&31; p=dwpos>>2, wi=dwpos&3;
    // g = p ^ (d&7)  (content octet);  source dword =
    //   (g>>2)*16 + ((wi>>1)&1)*8 + (g&3)*2 + (wi&1)   [relabel math, proven r9]
    const int vrow_off = lane >> 5;              // 0/1 within the 2-row pair
    const int dwpos = lane & 31;
    const int p_oct = dwpos >> 2, w_i = dwpos & 3;

    // Q fragment (B-op): B[k=d=quad*8+j][n=query=l15]; zero for d>=16
    s16x8 aq = {0, 0, 0, 0, 0, 0, 0, 0};
    if (quad < 2)
        aq = *(const s16x8*)&qws[(bh * 3136 + nb + l15) * 16 + quad * 8];
    s16x8 ones;
    #pragma unroll
    for (int i = 0; i < 8; i++) ones[i] = (short)0x3F80;   // bf16 1.0

    f32x4 acc[4], acc5;                          // O^T tiles + rowsum tile
    #pragma unroll
    for (int dt = 0; dt < 4; dt++) acc[dt] = (f32x4){0.f, 0.f, 0.f, 0.f};
    acc5 = (f32x4){0.f, 0.f, 0.f, 0.f};

    // ---- stage one chunk (9 DMA per wave)
    auto stage_chunk = [&](int kbase, int buf) {
        #pragma unroll
        for (int s = 0; s < 2; s++) {
            const int m0 = wave + s * 4;         // two 4-row pair-groups/wave
            #pragma unroll
            for (int h = 0; h < 4; h++) {
                const int m = m0 * 4 + h;        // pair index 0..31? no:
                // m in [0,32): wave covers m = wave*?; use m = (s*4+wave)*4+h
                const int d = 2 * m + vrow_off;
                const int g = p_oct ^ (d & 7);
                const int src_dw = (g >> 2) * 16 + ((w_i >> 1) & 1) * 8 +
                                   (g & 3) * 2 + (w_i & 1);
                stage4(vb + d * 3136 + kbase + src_dw * 2,
                       &stg[buf][1024 + m * 128]);
            }
        }
        stage16(kb + (kbase + ksrc_row) * 16 + khalf * 8, &stg[buf][kdst]);
    };

    stage_chunk(0, 0);
    stage_chunk(64, 1);
    __builtin_amdgcn_s_waitcnt(0x0F79);          // vmcnt(9): chunk0 landed (mine)

    for (int c = 0; c < 49; c++) {
        __builtin_amdgcn_s_barrier();            // chunk c certified block-wide;
                                                 // readers of buf (c+2)%3 done
        const int cs = (c + 2 < 49) ? (c + 2) : 48;
        stage_chunk(cs * 64, (c + 2) % 3);
        __builtin_amdgcn_s_waitcnt(0x0F79);      // vmcnt(9): chunk c+1 landed

        const u16* kc_ = &stg[c % 3][0];
        const u16* vc_ = &stg[c % 3][1024];
        const f32x4 z = {0.f, 0.f, 0.f, 0.f};

        // ---- S^T = K·Q^T : 4 key tiles of 16 (swapped operands; r8 proven)
        f32x4 s[4];
        #pragma unroll
        for (int i = 0; i < 4; i++) {
            s16x8 kf = *(const s16x8*)&kc_[(i * 16 + l15) * 16 +
                                           (((quad & 1) ^ ((l15 >> 2) & 1)) * 8)];
            s[i] = mfma32(kf, aq, z);
        }

        // ---- P pack (r9 proven): pf[c32] = {exp2 s[2c32], exp2 s[2c32+1]}
        s16x8 pf[2];
        #pragma unroll
        for (int c32 = 0; c32 < 2; c32++) {
            #pragma unroll
            for (int r = 0; r < 4; r++) {
                pf[c32][r]     = (short)f2bf_h(__builtin_amdgcn_exp2f(s[2 * c32][r]));
                pf[c32][4 + r] = (short)f2bf_h(__builtin_amdgcn_exp2f(s[2 * c32 + 1][r]));
            }
        }

        // ---- O^T += V^T·P : A-frag = one b128 (octet o_rel^(d&7)); rowsum MFMA
        #pragma unroll
        for (int c32 = 0; c32 < 2; c32++) {
            #pragma unroll
            for (int dt = 0; dt < 4; dt++) {
                const int d = dt * 16 + l15;
                const int pos = ((c32 * 4 + quad) ^ (d & 7)) * 8;
                s16x8 vf = *(const s16x8*)&vc_[d * 64 + pos];
                acc[dt] = mfma32(vf, pf[c32], acc[dt]);
            }
            acc5 = mfma32(ones, pf[c32], acc5);
        }
    }

    const float inv = 1.0f / acc5[0];            // rowsum for query l15

    // ---- epilogue (r9 proven): O^T rows d=dt*16+quad*4+r, col l15
    u16* dst = &o_t[(((bh >> 3) * 3136) + nb + l15) * 512 + (bh & 7) * 64];
    #pragma unroll
    for (int dt = 0; dt < 4; dt++) {
        u16x4 o4;
        #pragma unroll
        for (int r = 0; r < 4; r++) o4[r] = f2bf(acc[dt][r] * inv);
        *(u16x4*)&dst[dt * 16 + quad * 4] = o4;
    }
}

// ---------------------------------------------------------------------------
// Output projection MFMA GEMM, no LDS. grid (98 n-tiles of 32, 4 och, 2 b).
// ---------------------------------------------------------------------------
__global__ __launch_bounds__(256, 4) void proj_kernel(
    const u16* __restrict__ o_t, const u16* __restrict__ wpb,
    const float* __restrict__ bp, float* __restrict__ out)
{
    const int b = blockIdx.z, n0 = blockIdx.x * 32;
    const int och0 = blockIdx.y * 64 + (threadIdx.x >> 6) * 16;
    const int lane = threadIdx.x & 63;
    const int l15 = lane & 15, quad = lane >> 4;
    const f32x4 z = {0.f, 0.f, 0.f, 0.f};

    const u16* arow = &wpb[(och0 + l15) * 512 + quad * 8];
    f32x4 acc[2] = {z, z};
    #pragma unroll 4
    for (int kc = 0; kc < 512; kc += 32) {
        s16x8 a = *(const s16x8*)&arow[kc];
        #pragma unroll
        for (int f = 0; f < 2; f++) {
            s16x8 bf = *(const s16x8*)&o_t[(b * 3136 + n0 + f * 16 + l15) * 512 + kc + quad * 8];
            acc[f] = mfma32(a, bf, acc[f]);
        }
    }
    #pragma unroll
    for (int r = 0; r < 4; r++) {
        const int och = och0 + quad * 4 + r;
        const float bi = bp[och];
        #pragma unroll
        for (int f = 0; f < 2; f++)
            out[(b * 256 + och) * 3136 + n0 + f * 16 + l15] = acc[f][r] + bi;
    }
}

// ---------------------------------------------------------------------------
extern "C" void kernel_launch(void* const* d_in, const int* in_sizes, int n_in,
                              void* d_out, int out_size, void* d_ws, size_t ws_size,
                              hipStream_t stream) {
    const float* x  = (const float*)d_in[0];
    const float* wq = (const float*)d_in[1];
    const float* sq = (const float*)d_in[2];
    const float* bq = (const float*)d_in[3];
    const float* wk = (const float*)d_in[4];
    const float* sk = (const float*)d_in[5];
    const float* bk = (const float*)d_in[6];
    const float* wv = (const float*)d_in[7];
    const float* sv = (const float*)d_in[8];
    const float* bv = (const float*)d_in[9];
    const float* wp = (const float*)d_in[10];
    const float* sp = (const float*)d_in[11];
    const float* bp = (const float*)d_in[12];
    float* out = (float*)d_out;

    u16* qws = (u16*)d_ws;                 // 802816
    u16* kws = qws + 802816;               // 802816
    u16* vws = kws + 802816;               // 3211264
    u16* R   = vws + 3211264;              // 3211264 (x_t then o_t, overlaid)
    u16* xt  = R;
    u16* ot  = R;
    u16* wqb = R + 3211264;                // 32768
    u16* wkb = wqb + 32768;                // 32768
    u16* wvb = wkb + 32768;                // 131072
    u16* wpb = wvb + 131072;               // 131072  (total 16,711,680 B)

    xtw_kernel<<<dim3(49, 4, 3), 256, 0, stream>>>(x, xt, wq, sq, wk, sk,
                                                   wv, sv, wp, sp,
                                                   wqb, wkb, wvb, wpb);
    qkv_kernel<<<dim3(49, 12, 2), 256, 0, stream>>>(xt, wqb, wkb, wvb,
                                                    bq, bk, bv, qws, kws, vws);
    attn_kernel<<<dim3(16, 49), 256, 0, stream>>>(qws, kws, vws, ot);
    proj_kernel<<<dim3(98, 4, 2), 256, 0, stream>>>(ot, wpb, bp, out);
}